// Round 12
// baseline (205.315 us; speedup 1.0000x reference)
//
#include <hip/hip_runtime.h>
#include <hip/hip_bf16.h>
#include <hip/hip_fp16.h>

#define N_NODES 10000
#define N_EDGES 640000
#define TOT_E   (N_EDGES + N_NODES)
#define HID     128
#define NEG_SLOPE 0.2f
#define N_ACT   4096

// ---- deterministic bucket counting-sort CSR build (no global atomics) ----
#define NBKT   250
#define NPB    40
#define P1_EPB 4096
#define P1_EPT 16
#define P1_BLOCKS 159
#define SLOTP  56
#define G_BLOCKS 313   // ceil(N_NODES/32) gemm-role blocks in merged kernel
#define AGG_B  2500    // one node per wave; HW block scheduler load-balances

__global__ __launch_bounds__(256) void part1_k(const int* __restrict__ ei,
                                               unsigned* __restrict__ bpart,
                                               int* __restrict__ bcnt) {
    __shared__ int hist[256];
    __shared__ int lofs[256];
    __shared__ int sc[256];
    __shared__ unsigned stage[P1_EPB];
    __shared__ unsigned char bkt_of[P1_EPB];
    int t = threadIdx.x;
    hist[t] = 0;
    __syncthreads();

    unsigned pk[P1_EPT];
    int bk[P1_EPT];
    int e0 = blockIdx.x * P1_EPB;
#pragma unroll
    for (int i = 0; i < P1_EPT; i++) {
        int e = e0 + i * 256 + t;
        if (e < TOT_E) {
            int src, dst;
            if (e < N_EDGES) { src = ei[e]; dst = ei[N_EDGES + e]; }
            else             { src = e - N_EDGES; dst = src; }
            pk[i] = ((unsigned)dst << 16) | (unsigned)src;
            bk[i] = dst / NPB;
            atomicAdd(&hist[bk[i]], 1);
        } else bk[i] = -1;
    }
    __syncthreads();
    int v = hist[t];
    sc[t] = v;
    __syncthreads();
    for (int o = 1; o < 256; o <<= 1) {
        int u = (t >= o) ? sc[t - o] : 0;
        __syncthreads();
        sc[t] += u;
        __syncthreads();
    }
    lofs[t] = sc[t] - v;
    bcnt[blockIdx.x * 256 + t] = v;
    hist[t] = 0;
    __syncthreads();
#pragma unroll
    for (int i = 0; i < P1_EPT; i++) {
        if (bk[i] >= 0) {
            int p = atomicAdd(&hist[bk[i]], 1);
            int slot = lofs[bk[i]] + p;
            stage[slot] = pk[i];
            bkt_of[slot] = (unsigned char)bk[i];
        }
    }
    __syncthreads();
    int nv = min(P1_EPB, TOT_E - e0);
    for (int s = t; s < nv; s += 256) {
        int b = bkt_of[s];
        bpart[b * (P1_BLOCKS * SLOTP) + blockIdx.x * SLOTP + (s - lofs[b])] = stage[s];
    }
}

__device__ __forceinline__ void gload_lds16(const float* g, float* l) {
    __builtin_amdgcn_global_load_lds(
        (const __attribute__((address_space(1))) void*)g,
        (__attribute__((address_space(3))) void*)l, 16, 0, 0);
}

// -------- shared gemm body: z16 = fp16(A@W), zs, zd (one-shot LDS residency) --------
__device__ __forceinline__ void gemm_body(const float* __restrict__ A,
                                          const float* __restrict__ W,
                                          const float* __restrict__ avs,
                                          const float* __restrict__ avd,
                                          __half* __restrict__ z16,
                                          float* __restrict__ zs,
                                          float* __restrict__ zd,
                                          float* smem, int blk, int t) {
    float* As = smem;            // 16 KB
    float* Ws = smem + 32 * HID; // 64 KB
    int w = t >> 6, lane = t & 63;
    int row0 = blk * 32;
#pragma unroll
    for (int i = 0; i < 4; i++) {
        int chunk = w * 4 + i;
        long foff = (long)row0 * HID + chunk * 256;
        const float* g = ((foff + 256) <= (long)N_NODES * HID) ? (A + foff + lane * 4)
                                                               : (A + lane * 4);
        gload_lds16(g, As + chunk * 256);
    }
#pragma unroll
    for (int i = 0; i < 16; i++) {
        int chunk = w * 16 + i;
        gload_lds16(W + chunk * 256 + lane * 4, Ws + chunk * 256);
    }
    __syncthreads();

    int tx = t & 31, ty = t >> 5;
    int r0 = ty * 4;
    float acc[4][4] = {{0.f}};
#pragma unroll 4
    for (int k4 = 0; k4 < 32; k4++) {
        float ak[4][4];
#pragma unroll
        for (int r = 0; r < 4; r++) {
            float4 a4 = *(const float4*)&As[(r0 + r) * HID + k4 * 4];
            ak[r][0] = a4.x; ak[r][1] = a4.y; ak[r][2] = a4.z; ak[r][3] = a4.w;
        }
        const float* Wb = &Ws[k4 * 4 * HID + tx * 4];
#pragma unroll
        for (int kk = 0; kk < 4; kk++) {
            float4 wv = *(const float4*)&Wb[kk * HID];
#pragma unroll
            for (int r = 0; r < 4; r++) {
                acc[r][0] = fmaf(ak[r][kk], wv.x, acc[r][0]);
                acc[r][1] = fmaf(ak[r][kk], wv.y, acc[r][1]);
                acc[r][2] = fmaf(ak[r][kk], wv.z, acc[r][2]);
                acc[r][3] = fmaf(ak[r][kk], wv.w, acc[r][3]);
            }
        }
    }
    float4 asv = *(const float4*)&avs[tx * 4];
    float4 adv = *(const float4*)&avd[tx * 4];
#pragma unroll
    for (int r = 0; r < 4; r++) {
        int row = row0 + r0 + r;
        if (row < N_NODES) {
            *(__half2*)&z16[row * HID + tx * 4]     = __floats2half2_rn(acc[r][0], acc[r][1]);
            *(__half2*)&z16[row * HID + tx * 4 + 2] = __floats2half2_rn(acc[r][2], acc[r][3]);
        }
        float ps = acc[r][0] * asv.x + acc[r][1] * asv.y + acc[r][2] * asv.z + acc[r][3] * asv.w;
        float pd = acc[r][0] * adv.x + acc[r][1] * adv.y + acc[r][2] * adv.z + acc[r][3] * adv.w;
#pragma unroll
        for (int o = 1; o < 32; o <<= 1) {
            ps += __shfl_xor(ps, o, 64);
            pd += __shfl_xor(pd, o, 64);
        }
        if (tx == 0 && row < N_NODES) { zs[row] = ps; zd[row] = pd; }
    }
}

// -------- merged: gemm0 (blocks < G_BLOCKS)  ||  part2 CSR finalize (rest) --------
__global__ __launch_bounds__(256) void g2_k(const float* __restrict__ A,
                                            const float* __restrict__ W,
                                            const float* __restrict__ avs,
                                            const float* __restrict__ avd,
                                            __half* __restrict__ z16,
                                            float* __restrict__ zs,
                                            float* __restrict__ zd,
                                            const unsigned* __restrict__ bpart,
                                            const int* __restrict__ bcnt,
                                            int* __restrict__ csr,
                                            int* __restrict__ offs) {
    __shared__ float smem[20480];   // 80 KB, carved per role
    int t = threadIdx.x;

    if (blockIdx.x < G_BLOCKS) {
        gemm_body(A, W, avs, avd, z16, zs, zd, smem, blockIdx.x, t);
    } else {
        // ---------------- part2 role: CSR finalize ----------------
        int b = blockIdx.x - G_BLOCKS;
        unsigned* ebuf = (unsigned*)smem;          // 16 KB
        int* sc    = (int*)(smem + 4096);          // 1 KB
        int* Ls    = sc + 256;                     // 1 KB
        int* nhist = Ls + 256;                     // 160 B
        __shared__ int bstart_s, cnt_s;

        int tot = 0;
        if (t < NBKT) {
            int t0 = 0, t1 = 0, t2 = 0, t3 = 0;
            int blk = 0;
            for (; blk + 4 <= P1_BLOCKS; blk += 4) {
                t0 += bcnt[(blk + 0) * 256 + t];
                t1 += bcnt[(blk + 1) * 256 + t];
                t2 += bcnt[(blk + 2) * 256 + t];
                t3 += bcnt[(blk + 3) * 256 + t];
            }
            for (; blk < P1_BLOCKS; blk++) t0 += bcnt[blk * 256 + t];
            tot = t0 + t1 + t2 + t3;
        }
        sc[t] = tot;
        __syncthreads();
        for (int o = 1; o < 256; o <<= 1) {
            int u = (t >= o) ? sc[t - o] : 0;
            __syncthreads();
            sc[t] += u;
            __syncthreads();
        }
        if (t == b) { bstart_s = sc[t] - tot; cnt_s = tot; }
        if (b == 0 && t == 255) offs[N_NODES] = sc[255];
        __syncthreads();

        int L = (t < P1_BLOCKS) ? bcnt[t * 256 + b] : 0;
        Ls[t] = L;
        sc[t] = L;
        __syncthreads();
        for (int o = 1; o < 256; o <<= 1) {
            int u = (t >= o) ? sc[t - o] : 0;
            __syncthreads();
            sc[t] += u;
            __syncthreads();
        }
        if (t < NPB) nhist[t] = 0;
        {
            int wv = t >> 6, lane = t & 63;
            const unsigned* bbase = bpart + b * (P1_BLOCKS * SLOTP);
            for (int r = wv; r < P1_BLOCKS; r += 4) {
                int Lr = Ls[r];
                if (lane < Lr) ebuf[(sc[r] - Lr) + lane] = bbase[r * SLOTP + lane];
            }
        }
        __syncthreads();

        int cnt = cnt_s;
        int n0 = b * NPB;
        for (int i = t; i < cnt; i += 256) atomicAdd(&nhist[(ebuf[i] >> 16) - n0], 1);
        __syncthreads();
        if (t < 64) {
            int v2 = (t < NPB) ? nhist[t] : 0;
            int s2 = v2;
            for (int o = 1; o < 64; o <<= 1) {
                int u = __shfl_up(s2, o, 64);
                if (t >= o) s2 += u;
            }
            if (t < NPB) {
                int ofs = bstart_s + s2 - v2;
                nhist[t] = ofs;
                offs[n0 + t] = ofs;
            }
        }
        __syncthreads();
        for (int i = t; i < cnt; i += 256) {
            unsigned pk = ebuf[i];
            int p = atomicAdd(&nhist[(pk >> 16) - n0], 1);
            csr[p] = pk & 0xFFFF;
        }
    }
}

// -------- standalone layer GEMM: h(f32) @ W -> z16, zs, zd --------
__global__ __launch_bounds__(256) void gemmh_k(const float* __restrict__ A,
                                               const float* __restrict__ W,
                                               const float* __restrict__ avs,
                                               const float* __restrict__ avd,
                                               __half* __restrict__ z16,
                                               float* __restrict__ zs,
                                               float* __restrict__ zd) {
    __shared__ float smem[20480];   // 80 KB
    gemm_body(A, W, avs, avd, z16, zs, zd, smem, blockIdx.x, threadIdx.x);
}

// -------- aggregate layer: softmax-weighted neighbor sum -> h (f32) --------
// R11 structure (one node/wave), phase-2 unrolled 4x: iterations are
// independent (pair from wave-local LDS, row load from pair), so deeper
// unroll doubles rows-in-flight per wave (TLP capped at 8 waves/SIMD;
// VGPR 28 -> ~45, still under the 64 cliff). 2 KB LDS, (256,8).
__global__ __launch_bounds__(256, 8) void agg_k(const __half* __restrict__ z16,
                                                const float* __restrict__ zs,
                                                const float* __restrict__ zd,
                                                const int* __restrict__ offs,
                                                const int* __restrict__ csr,
                                                const float* __restrict__ b,
                                                float* __restrict__ hout) {
    __shared__ float2 sx[4][64];   // per-wave (ex, s) staging: 2 KB
    int t = threadIdx.x;
    int w = t >> 6, lane = t & 63;
    int grp = lane >> 4, l16 = lane & 15;
    const char* zb = (const char*)z16;
    unsigned loff = l16 * 16;
    int n = blockIdx.x * 4 + w;
    if (n < N_NODES) {
        int o0 = offs[n];
        int deg = offs[n + 1] - o0;
        float zdn = zd[n];
        float acc[8] = {0.f, 0.f, 0.f, 0.f, 0.f, 0.f, 0.f, 0.f};
        float denomv = 0.f;
        for (int base = 0; base < deg; base += 64) {
            int j = base + lane;
            int sreg = 0;
            float ex = 0.f;
            if (j < deg) {
                int s = csr[o0 + j];
                sreg = s;
                float e = zs[s] + zdn;
                e = e > 0.f ? e : NEG_SLOPE * e;
                ex = __expf(e);
            }
            sx[w][lane] = make_float2(ex, __int_as_float(sreg));
            // wave-synchronous write->read; compiler inserts the lgkmcnt wait
            int cnt = min(64, deg - base);
#pragma unroll 4
            for (int q = 0; q < cnt; q += 4) {
                float2 p = sx[w][q + grp];             // broadcast ds_read_b64
                float exv = p.x;                       // (ex=0 tail lanes -> no-op)
                unsigned sqv = (unsigned)__float_as_int(p.y);
                float4 rv = *(const float4*)(zb + sqv * 256u + loff);
                denomv += exv;
                const __half2* hp = (const __half2*)&rv;
#pragma unroll
                for (int u = 0; u < 4; u++) {
                    float2 f = __half22float2(hp[u]);
                    acc[2 * u]     = fmaf(exv, f.x, acc[2 * u]);
                    acc[2 * u + 1] = fmaf(exv, f.y, acc[2 * u + 1]);
                }
            }
        }
        // combine the 4 edge-groups (xor bits 4,5 of lane)
#pragma unroll
        for (int u = 0; u < 8; u++) {
            acc[u] += __shfl_xor(acc[u], 16, 64);
            acc[u] += __shfl_xor(acc[u], 32, 64);
        }
        denomv += __shfl_xor(denomv, 16, 64);
        denomv += __shfl_xor(denomv, 32, 64);
        if (lane < 16) {
            float inv = 1.0f / denomv;
            float4 b0 = *(const float4*)&b[l16 * 8];
            float4 b1 = *(const float4*)&b[l16 * 8 + 4];
            float4 o0v, o1v;
            o0v.x = fmaxf(fmaf(acc[0], inv, b0.x), 0.f);
            o0v.y = fmaxf(fmaf(acc[1], inv, b0.y), 0.f);
            o0v.z = fmaxf(fmaf(acc[2], inv, b0.z), 0.f);
            o0v.w = fmaxf(fmaf(acc[3], inv, b0.w), 0.f);
            o1v.x = fmaxf(fmaf(acc[4], inv, b1.x), 0.f);
            o1v.y = fmaxf(fmaf(acc[5], inv, b1.y), 0.f);
            o1v.z = fmaxf(fmaf(acc[6], inv, b1.z), 0.f);
            o1v.w = fmaxf(fmaf(acc[7], inv, b1.w), 0.f);
            *(float4*)&hout[(long)n * HID + l16 * 8]     = o0v;
            *(float4*)&hout[(long)n * HID + l16 * 8 + 4] = o1v;
        }
    }
}

// -------- action scoring: tiled GEMM, 16 actions/block × 256 blocks, dbuf W1 --------

#define SC_APB 16

__global__ __launch_bounds__(256) void score_k(const float* __restrict__ h,
                                               const int* __restrict__ asrc,
                                               const int* __restrict__ adst,
                                               const int* __restrict__ atype,
                                               const float* __restrict__ W1,
                                               const float* __restrict__ b1,
                                               const float* __restrict__ W2,
                                               const float* __restrict__ b2,
                                               float* __restrict__ out) {
    __shared__ float featT[257][SC_APB + 1];   // [k][action], padded: 17.5 KB
    __shared__ float Wc[2][32 * HID];          // 32 KB
    int t = threadIdx.x;
    int a0 = blockIdx.x * SC_APB;

    float4 wreg[4];
    {
        const float4* Wg = (const float4*)W1;
#pragma unroll
        for (int i = 0; i < 4; i++) wreg[i] = Wg[t + 256 * i];
    }
    for (int idx = t; idx < SC_APB * 128; idx += 256) {
        int a = idx >> 7, c = idx & 127;
        featT[c][a]       = h[asrc[a0 + a] * HID + c];
        featT[128 + c][a] = h[adst[a0 + a] * HID + c];
    }
    if (t < SC_APB) featT[256][t] = (float)atype[a0 + t];

    int cg = t & 31, ap = t >> 5;
    float4 bv = *(const float4*)&b1[cg * 4];
    float acc0[4] = {bv.x, bv.y, bv.z, bv.w};
    float acc1[4] = {bv.x, bv.y, bv.z, bv.w};

    for (int c = 0; c < 8; c++) {
        float4* dstb = (float4*)Wc[c & 1];
#pragma unroll
        for (int i = 0; i < 4; i++) dstb[t + 256 * i] = wreg[i];
        __syncthreads();
        if (c + 1 < 8) {
            const float4* Wg = (const float4*)(W1 + (c + 1) * 32 * HID);
#pragma unroll
            for (int i = 0; i < 4; i++) wreg[i] = Wg[t + 256 * i];
        }
        const float* Wb = Wc[c & 1];
        const float* fT = &featT[c * 32][0];
#pragma unroll 8
        for (int kk = 0; kk < 32; kk++) {
            float4 wv = *(const float4*)&Wb[kk * HID + cg * 4];
            float f0 = fT[kk * (SC_APB + 1) + ap * 2];
            float f1 = fT[kk * (SC_APB + 1) + ap * 2 + 1];
            acc0[0] = fmaf(f0, wv.x, acc0[0]);
            acc0[1] = fmaf(f0, wv.y, acc0[1]);
            acc0[2] = fmaf(f0, wv.z, acc0[2]);
            acc0[3] = fmaf(f0, wv.w, acc0[3]);
            acc1[0] = fmaf(f1, wv.x, acc1[0]);
            acc1[1] = fmaf(f1, wv.y, acc1[1]);
            acc1[2] = fmaf(f1, wv.z, acc1[2]);
            acc1[3] = fmaf(f1, wv.w, acc1[3]);
        }
    }
    {
        float4 wv = *(const float4*)&W1[256 * HID + cg * 4];
        float f0 = featT[256][ap * 2];
        float f1 = featT[256][ap * 2 + 1];
        acc0[0] = fmaf(f0, wv.x, acc0[0]); acc0[1] = fmaf(f0, wv.y, acc0[1]);
        acc0[2] = fmaf(f0, wv.z, acc0[2]); acc0[3] = fmaf(f0, wv.w, acc0[3]);
        acc1[0] = fmaf(f1, wv.x, acc1[0]); acc1[1] = fmaf(f1, wv.y, acc1[1]);
        acc1[2] = fmaf(f1, wv.z, acc1[2]); acc1[3] = fmaf(f1, wv.w, acc1[3]);
    }
    float4 w2v = *(const float4*)&W2[cg * 4];
    float v0 = 0.f, v1 = 0.f;
    v0 += (acc0[0] > 0.f ? acc0[0] : 0.f) * w2v.x;
    v0 += (acc0[1] > 0.f ? acc0[1] : 0.f) * w2v.y;
    v0 += (acc0[2] > 0.f ? acc0[2] : 0.f) * w2v.z;
    v0 += (acc0[3] > 0.f ? acc0[3] : 0.f) * w2v.w;
    v1 += (acc1[0] > 0.f ? acc1[0] : 0.f) * w2v.x;
    v1 += (acc1[1] > 0.f ? acc1[1] : 0.f) * w2v.y;
    v1 += (acc1[2] > 0.f ? acc1[2] : 0.f) * w2v.z;
    v1 += (acc1[3] > 0.f ? acc1[3] : 0.f) * w2v.w;
#pragma unroll
    for (int o = 1; o < 32; o <<= 1) {
        v0 += __shfl_xor(v0, o, 64);
        v1 += __shfl_xor(v1, o, 64);
    }
    if (cg == 0) {
        out[a0 + ap * 2]     = v0 + b2[0];
        out[a0 + ap * 2 + 1] = v1 + b2[0];
    }
}

// ---------------- launch ----------------

extern "C" void kernel_launch(void* const* d_in, const int* in_sizes, int n_in,
                              void* d_out, int out_size, void* d_ws, size_t ws_size,
                              hipStream_t stream) {
    const float* x   = (const float*)d_in[0];
    const int* ei    = (const int*)d_in[1];
    const int* asrc  = (const int*)d_in[2];
    const int* adst  = (const int*)d_in[3];
    const int* atype = (const int*)d_in[4];
    const float* gW  = (const float*)d_in[5];
    const float* gas = (const float*)d_in[6];
    const float* gad = (const float*)d_in[7];
    const float* gb  = (const float*)d_in[8];
    const float* W1  = (const float*)d_in[9];
    const float* b1  = (const float*)d_in[10];
    const float* W2  = (const float*)d_in[11];
    const float* b2  = (const float*)d_in[12];
    float* out = (float*)d_out;

    __half* z16A = (__half*)d_ws;                       // 2.56 MB
    __half* z16B = z16A + N_NODES * HID;                // 2.56 MB
    float* H    = (float*)(z16B + N_NODES * HID);       // 5.12 MB (shared h buffer)
    float* zsA  = H + N_NODES * HID;
    float* zdA  = zsA + N_NODES;
    float* zsB  = zdA + N_NODES;
    float* zdB  = zsB + N_NODES;
    int* offs   = (int*)(zdB + N_NODES);
    int* csr    = offs + (N_NODES + 1);
    int* bcnt   = csr + TOT_E;
    unsigned* bpart = (unsigned*)(bcnt + P1_BLOCKS * 256);

    part1_k<<<P1_BLOCKS, 256, 0, stream>>>(ei, bpart, bcnt);
    g2_k<<<G_BLOCKS + NBKT, 256, 0, stream>>>(x, gW, gas, gad, z16A, zsA, zdA,
                                              bpart, bcnt, csr, offs);

    // layer 1: agg -> H -> gemm -> z16B
    agg_k<<<AGG_B, 256, 0, stream>>>(z16A, zsA, zdA, offs, csr, gb, H);
    gemmh_k<<<G_BLOCKS, 256, 0, stream>>>(H, gW + 1 * HID * HID, gas + 1 * HID,
                                          gad + 1 * HID, z16B, zsB, zdB);
    // layer 2: agg -> H -> gemm -> z16A
    agg_k<<<AGG_B, 256, 0, stream>>>(z16B, zsB, zdB, offs, csr, gb + 1 * HID, H);
    gemmh_k<<<G_BLOCKS, 256, 0, stream>>>(H, gW + 2 * HID * HID, gas + 2 * HID,
                                          gad + 2 * HID, z16A, zsA, zdA);
    // layer 3: agg -> H (final node embeddings)
    agg_k<<<AGG_B, 256, 0, stream>>>(z16A, zsA, zdA, offs, csr, gb + 2 * HID, H);

    score_k<<<N_ACT / SC_APB, 256, 0, stream>>>(H, asrc, adst, atype,
                                                W1, b1, W2, b2, out);
}

// Round 13
// 200.661 us; speedup vs baseline: 1.0232x; 1.0232x over previous
//
#include <hip/hip_runtime.h>
#include <hip/hip_bf16.h>
#include <hip/hip_fp16.h>

#define N_NODES 10000
#define N_EDGES 640000
#define TOT_E   (N_EDGES + N_NODES)
#define HID     128
#define NEG_SLOPE 0.2f
#define N_ACT   4096

// ---- deterministic bucket counting-sort CSR build (no global atomics) ----
#define NBKT   250
#define NPB    40
#define P1_EPB 4096
#define P1_EPT 16
#define P1_BLOCKS 159
#define SLOTP  56
#define G_BLOCKS 313   // ceil(N_NODES/32) gemm-role blocks in merged kernel
#define AGG_B  2500    // one node per wave; HW block scheduler load-balances

__global__ __launch_bounds__(256) void part1_k(const int* __restrict__ ei,
                                               unsigned* __restrict__ bpart,
                                               int* __restrict__ bcnt) {
    __shared__ int hist[256];
    __shared__ int lofs[256];
    __shared__ int sc[256];
    __shared__ unsigned stage[P1_EPB];
    __shared__ unsigned char bkt_of[P1_EPB];
    int t = threadIdx.x;
    hist[t] = 0;
    __syncthreads();

    unsigned pk[P1_EPT];
    int bk[P1_EPT];
    int e0 = blockIdx.x * P1_EPB;
#pragma unroll
    for (int i = 0; i < P1_EPT; i++) {
        int e = e0 + i * 256 + t;
        if (e < TOT_E) {
            int src, dst;
            if (e < N_EDGES) { src = ei[e]; dst = ei[N_EDGES + e]; }
            else             { src = e - N_EDGES; dst = src; }
            pk[i] = ((unsigned)dst << 16) | (unsigned)src;
            bk[i] = dst / NPB;
            atomicAdd(&hist[bk[i]], 1);
        } else bk[i] = -1;
    }
    __syncthreads();
    int v = hist[t];
    sc[t] = v;
    __syncthreads();
    for (int o = 1; o < 256; o <<= 1) {
        int u = (t >= o) ? sc[t - o] : 0;
        __syncthreads();
        sc[t] += u;
        __syncthreads();
    }
    lofs[t] = sc[t] - v;
    bcnt[blockIdx.x * 256 + t] = v;
    hist[t] = 0;
    __syncthreads();
#pragma unroll
    for (int i = 0; i < P1_EPT; i++) {
        if (bk[i] >= 0) {
            int p = atomicAdd(&hist[bk[i]], 1);
            int slot = lofs[bk[i]] + p;
            stage[slot] = pk[i];
            bkt_of[slot] = (unsigned char)bk[i];
        }
    }
    __syncthreads();
    int nv = min(P1_EPB, TOT_E - e0);
    for (int s = t; s < nv; s += 256) {
        int b = bkt_of[s];
        bpart[b * (P1_BLOCKS * SLOTP) + blockIdx.x * SLOTP + (s - lofs[b])] = stage[s];
    }
}

__device__ __forceinline__ void gload_lds16(const float* g, float* l) {
    __builtin_amdgcn_global_load_lds(
        (const __attribute__((address_space(1))) void*)g,
        (__attribute__((address_space(3))) void*)l, 16, 0, 0);
}

// -------- shared gemm body: z16 = fp16(A@W), zs, zd (one-shot LDS residency) --------
__device__ __forceinline__ void gemm_body(const float* __restrict__ A,
                                          const float* __restrict__ W,
                                          const float* __restrict__ avs,
                                          const float* __restrict__ avd,
                                          __half* __restrict__ z16,
                                          float* __restrict__ zs,
                                          float* __restrict__ zd,
                                          float* smem, int blk, int t) {
    float* As = smem;            // 16 KB
    float* Ws = smem + 32 * HID; // 64 KB
    int w = t >> 6, lane = t & 63;
    int row0 = blk * 32;
#pragma unroll
    for (int i = 0; i < 4; i++) {
        int chunk = w * 4 + i;
        long foff = (long)row0 * HID + chunk * 256;
        const float* g = ((foff + 256) <= (long)N_NODES * HID) ? (A + foff + lane * 4)
                                                               : (A + lane * 4);
        gload_lds16(g, As + chunk * 256);
    }
#pragma unroll
    for (int i = 0; i < 16; i++) {
        int chunk = w * 16 + i;
        gload_lds16(W + chunk * 256 + lane * 4, Ws + chunk * 256);
    }
    __syncthreads();

    int tx = t & 31, ty = t >> 5;
    int r0 = ty * 4;
    float acc[4][4] = {{0.f}};
#pragma unroll 4
    for (int k4 = 0; k4 < 32; k4++) {
        float ak[4][4];
#pragma unroll
        for (int r = 0; r < 4; r++) {
            float4 a4 = *(const float4*)&As[(r0 + r) * HID + k4 * 4];
            ak[r][0] = a4.x; ak[r][1] = a4.y; ak[r][2] = a4.z; ak[r][3] = a4.w;
        }
        const float* Wb = &Ws[k4 * 4 * HID + tx * 4];
#pragma unroll
        for (int kk = 0; kk < 4; kk++) {
            float4 wv = *(const float4*)&Wb[kk * HID];
#pragma unroll
            for (int r = 0; r < 4; r++) {
                acc[r][0] = fmaf(ak[r][kk], wv.x, acc[r][0]);
                acc[r][1] = fmaf(ak[r][kk], wv.y, acc[r][1]);
                acc[r][2] = fmaf(ak[r][kk], wv.z, acc[r][2]);
                acc[r][3] = fmaf(ak[r][kk], wv.w, acc[r][3]);
            }
        }
    }
    float4 asv = *(const float4*)&avs[tx * 4];
    float4 adv = *(const float4*)&avd[tx * 4];
#pragma unroll
    for (int r = 0; r < 4; r++) {
        int row = row0 + r0 + r;
        if (row < N_NODES) {
            *(__half2*)&z16[row * HID + tx * 4]     = __floats2half2_rn(acc[r][0], acc[r][1]);
            *(__half2*)&z16[row * HID + tx * 4 + 2] = __floats2half2_rn(acc[r][2], acc[r][3]);
        }
        float ps = acc[r][0] * asv.x + acc[r][1] * asv.y + acc[r][2] * asv.z + acc[r][3] * asv.w;
        float pd = acc[r][0] * adv.x + acc[r][1] * adv.y + acc[r][2] * adv.z + acc[r][3] * adv.w;
#pragma unroll
        for (int o = 1; o < 32; o <<= 1) {
            ps += __shfl_xor(ps, o, 64);
            pd += __shfl_xor(pd, o, 64);
        }
        if (tx == 0 && row < N_NODES) { zs[row] = ps; zd[row] = pd; }
    }
}

// -------- merged: gemm0 (blocks < G_BLOCKS)  ||  part2 CSR finalize (rest) --------
__global__ __launch_bounds__(256) void g2_k(const float* __restrict__ A,
                                            const float* __restrict__ W,
                                            const float* __restrict__ avs,
                                            const float* __restrict__ avd,
                                            __half* __restrict__ z16,
                                            float* __restrict__ zs,
                                            float* __restrict__ zd,
                                            const unsigned* __restrict__ bpart,
                                            const int* __restrict__ bcnt,
                                            int* __restrict__ csr,
                                            int* __restrict__ offs) {
    __shared__ float smem[20480];   // 80 KB, carved per role
    int t = threadIdx.x;

    if (blockIdx.x < G_BLOCKS) {
        gemm_body(A, W, avs, avd, z16, zs, zd, smem, blockIdx.x, t);
    } else {
        // ---------------- part2 role: CSR finalize ----------------
        int b = blockIdx.x - G_BLOCKS;
        unsigned* ebuf = (unsigned*)smem;          // 16 KB
        int* sc    = (int*)(smem + 4096);          // 1 KB
        int* Ls    = sc + 256;                     // 1 KB
        int* nhist = Ls + 256;                     // 160 B
        __shared__ int bstart_s, cnt_s;

        int tot = 0;
        if (t < NBKT) {
            int t0 = 0, t1 = 0, t2 = 0, t3 = 0;
            int blk = 0;
            for (; blk + 4 <= P1_BLOCKS; blk += 4) {
                t0 += bcnt[(blk + 0) * 256 + t];
                t1 += bcnt[(blk + 1) * 256 + t];
                t2 += bcnt[(blk + 2) * 256 + t];
                t3 += bcnt[(blk + 3) * 256 + t];
            }
            for (; blk < P1_BLOCKS; blk++) t0 += bcnt[blk * 256 + t];
            tot = t0 + t1 + t2 + t3;
        }
        sc[t] = tot;
        __syncthreads();
        for (int o = 1; o < 256; o <<= 1) {
            int u = (t >= o) ? sc[t - o] : 0;
            __syncthreads();
            sc[t] += u;
            __syncthreads();
        }
        if (t == b) { bstart_s = sc[t] - tot; cnt_s = tot; }
        if (b == 0 && t == 255) offs[N_NODES] = sc[255];
        __syncthreads();

        int L = (t < P1_BLOCKS) ? bcnt[t * 256 + b] : 0;
        Ls[t] = L;
        sc[t] = L;
        __syncthreads();
        for (int o = 1; o < 256; o <<= 1) {
            int u = (t >= o) ? sc[t - o] : 0;
            __syncthreads();
            sc[t] += u;
            __syncthreads();
        }
        if (t < NPB) nhist[t] = 0;
        {
            int wv = t >> 6, lane = t & 63;
            const unsigned* bbase = bpart + b * (P1_BLOCKS * SLOTP);
            for (int r = wv; r < P1_BLOCKS; r += 4) {
                int Lr = Ls[r];
                if (lane < Lr) ebuf[(sc[r] - Lr) + lane] = bbase[r * SLOTP + lane];
            }
        }
        __syncthreads();

        int cnt = cnt_s;
        int n0 = b * NPB;
        for (int i = t; i < cnt; i += 256) atomicAdd(&nhist[(ebuf[i] >> 16) - n0], 1);
        __syncthreads();
        if (t < 64) {
            int v2 = (t < NPB) ? nhist[t] : 0;
            int s2 = v2;
            for (int o = 1; o < 64; o <<= 1) {
                int u = __shfl_up(s2, o, 64);
                if (t >= o) s2 += u;
            }
            if (t < NPB) {
                int ofs = bstart_s + s2 - v2;
                nhist[t] = ofs;
                offs[n0 + t] = ofs;
            }
        }
        __syncthreads();
        for (int i = t; i < cnt; i += 256) {
            unsigned pk = ebuf[i];
            int p = atomicAdd(&nhist[(pk >> 16) - n0], 1);
            csr[p] = pk & 0xFFFF;
        }
    }
}

// -------- standalone layer GEMM: h(f32) @ W -> z16, zs, zd --------
__global__ __launch_bounds__(256) void gemmh_k(const float* __restrict__ A,
                                               const float* __restrict__ W,
                                               const float* __restrict__ avs,
                                               const float* __restrict__ avd,
                                               __half* __restrict__ z16,
                                               float* __restrict__ zs,
                                               float* __restrict__ zd) {
    __shared__ float smem[20480];   // 80 KB
    gemm_body(A, W, avs, avd, z16, zs, zd, smem, blockIdx.x, threadIdx.x);
}

// -------- aggregate layer: softmax-weighted neighbor sum -> h (f32) --------
// R9 two-phase structure, ONE node per wave (2500 blocks x 4 waves = 10000).
// 2048 blocks resident; the HW block dispatcher backfills as blocks retire
// -> load balancing with zero atomics. Phase-2 unroll 2 (unroll 4 measured
// WORSE, R12). Per-node math identical across rounds -> bitwise-same output.
// 2 KB LDS, (256,8): 32 waves/CU.
__global__ __launch_bounds__(256, 8) void agg_k(const __half* __restrict__ z16,
                                                const float* __restrict__ zs,
                                                const float* __restrict__ zd,
                                                const int* __restrict__ offs,
                                                const int* __restrict__ csr,
                                                const float* __restrict__ b,
                                                float* __restrict__ hout) {
    __shared__ float2 sx[4][64];   // per-wave (ex, s) staging: 2 KB
    int t = threadIdx.x;
    int w = t >> 6, lane = t & 63;
    int grp = lane >> 4, l16 = lane & 15;
    const char* zb = (const char*)z16;
    unsigned loff = l16 * 16;
    int n = blockIdx.x * 4 + w;
    if (n < N_NODES) {
        int o0 = offs[n];
        int deg = offs[n + 1] - o0;
        float zdn = zd[n];
        float acc[8] = {0.f, 0.f, 0.f, 0.f, 0.f, 0.f, 0.f, 0.f};
        float denomv = 0.f;
        for (int base = 0; base < deg; base += 64) {
            int j = base + lane;
            int sreg = 0;
            float ex = 0.f;
            if (j < deg) {
                int s = csr[o0 + j];
                sreg = s;
                float e = zs[s] + zdn;
                e = e > 0.f ? e : NEG_SLOPE * e;
                ex = __expf(e);
            }
            sx[w][lane] = make_float2(ex, __int_as_float(sreg));
            // wave-synchronous write->read; compiler inserts the lgkmcnt wait
            int cnt = min(64, deg - base);
#pragma unroll 2
            for (int q = 0; q < cnt; q += 4) {
                float2 p = sx[w][q + grp];             // broadcast ds_read_b64
                float exv = p.x;                       // (ex=0 tail lanes -> no-op)
                unsigned sqv = (unsigned)__float_as_int(p.y);
                float4 rv = *(const float4*)(zb + sqv * 256u + loff);
                denomv += exv;
                const __half2* hp = (const __half2*)&rv;
#pragma unroll
                for (int u = 0; u < 4; u++) {
                    float2 f = __half22float2(hp[u]);
                    acc[2 * u]     = fmaf(exv, f.x, acc[2 * u]);
                    acc[2 * u + 1] = fmaf(exv, f.y, acc[2 * u + 1]);
                }
            }
        }
        // combine the 4 edge-groups (xor bits 4,5 of lane)
#pragma unroll
        for (int u = 0; u < 8; u++) {
            acc[u] += __shfl_xor(acc[u], 16, 64);
            acc[u] += __shfl_xor(acc[u], 32, 64);
        }
        denomv += __shfl_xor(denomv, 16, 64);
        denomv += __shfl_xor(denomv, 32, 64);
        if (lane < 16) {
            float inv = 1.0f / denomv;
            float4 b0 = *(const float4*)&b[l16 * 8];
            float4 b1 = *(const float4*)&b[l16 * 8 + 4];
            float4 o0v, o1v;
            o0v.x = fmaxf(fmaf(acc[0], inv, b0.x), 0.f);
            o0v.y = fmaxf(fmaf(acc[1], inv, b0.y), 0.f);
            o0v.z = fmaxf(fmaf(acc[2], inv, b0.z), 0.f);
            o0v.w = fmaxf(fmaf(acc[3], inv, b0.w), 0.f);
            o1v.x = fmaxf(fmaf(acc[4], inv, b1.x), 0.f);
            o1v.y = fmaxf(fmaf(acc[5], inv, b1.y), 0.f);
            o1v.z = fmaxf(fmaf(acc[6], inv, b1.z), 0.f);
            o1v.w = fmaxf(fmaf(acc[7], inv, b1.w), 0.f);
            *(float4*)&hout[(long)n * HID + l16 * 8]     = o0v;
            *(float4*)&hout[(long)n * HID + l16 * 8 + 4] = o1v;
        }
    }
}

// -------- action scoring: tiled GEMM, 16 actions/block × 256 blocks, dbuf W1 --------

#define SC_APB 16

__global__ __launch_bounds__(256) void score_k(const float* __restrict__ h,
                                               const int* __restrict__ asrc,
                                               const int* __restrict__ adst,
                                               const int* __restrict__ atype,
                                               const float* __restrict__ W1,
                                               const float* __restrict__ b1,
                                               const float* __restrict__ W2,
                                               const float* __restrict__ b2,
                                               float* __restrict__ out) {
    __shared__ float featT[257][SC_APB + 1];   // [k][action], padded: 17.5 KB
    __shared__ float Wc[2][32 * HID];          // 32 KB
    int t = threadIdx.x;
    int a0 = blockIdx.x * SC_APB;

    float4 wreg[4];
    {
        const float4* Wg = (const float4*)W1;
#pragma unroll
        for (int i = 0; i < 4; i++) wreg[i] = Wg[t + 256 * i];
    }
    for (int idx = t; idx < SC_APB * 128; idx += 256) {
        int a = idx >> 7, c = idx & 127;
        featT[c][a]       = h[asrc[a0 + a] * HID + c];
        featT[128 + c][a] = h[adst[a0 + a] * HID + c];
    }
    if (t < SC_APB) featT[256][t] = (float)atype[a0 + t];

    int cg = t & 31, ap = t >> 5;
    float4 bv = *(const float4*)&b1[cg * 4];
    float acc0[4] = {bv.x, bv.y, bv.z, bv.w};
    float acc1[4] = {bv.x, bv.y, bv.z, bv.w};

    for (int c = 0; c < 8; c++) {
        float4* dstb = (float4*)Wc[c & 1];
#pragma unroll
        for (int i = 0; i < 4; i++) dstb[t + 256 * i] = wreg[i];
        __syncthreads();
        if (c + 1 < 8) {
            const float4* Wg = (const float4*)(W1 + (c + 1) * 32 * HID);
#pragma unroll
            for (int i = 0; i < 4; i++) wreg[i] = Wg[t + 256 * i];
        }
        const float* Wb = Wc[c & 1];
        const float* fT = &featT[c * 32][0];
#pragma unroll 8
        for (int kk = 0; kk < 32; kk++) {
            float4 wv = *(const float4*)&Wb[kk * HID + cg * 4];
            float f0 = fT[kk * (SC_APB + 1) + ap * 2];
            float f1 = fT[kk * (SC_APB + 1) + ap * 2 + 1];
            acc0[0] = fmaf(f0, wv.x, acc0[0]);
            acc0[1] = fmaf(f0, wv.y, acc0[1]);
            acc0[2] = fmaf(f0, wv.z, acc0[2]);
            acc0[3] = fmaf(f0, wv.w, acc0[3]);
            acc1[0] = fmaf(f1, wv.x, acc1[0]);
            acc1[1] = fmaf(f1, wv.y, acc1[1]);
            acc1[2] = fmaf(f1, wv.z, acc1[2]);
            acc1[3] = fmaf(f1, wv.w, acc1[3]);
        }
    }
    {
        float4 wv = *(const float4*)&W1[256 * HID + cg * 4];
        float f0 = featT[256][ap * 2];
        float f1 = featT[256][ap * 2 + 1];
        acc0[0] = fmaf(f0, wv.x, acc0[0]); acc0[1] = fmaf(f0, wv.y, acc0[1]);
        acc0[2] = fmaf(f0, wv.z, acc0[2]); acc0[3] = fmaf(f0, wv.w, acc0[3]);
        acc1[0] = fmaf(f1, wv.x, acc1[0]); acc1[1] = fmaf(f1, wv.y, acc1[1]);
        acc1[2] = fmaf(f1, wv.z, acc1[2]); acc1[3] = fmaf(f1, wv.w, acc1[3]);
    }
    float4 w2v = *(const float4*)&W2[cg * 4];
    float v0 = 0.f, v1 = 0.f;
    v0 += (acc0[0] > 0.f ? acc0[0] : 0.f) * w2v.x;
    v0 += (acc0[1] > 0.f ? acc0[1] : 0.f) * w2v.y;
    v0 += (acc0[2] > 0.f ? acc0[2] : 0.f) * w2v.z;
    v0 += (acc0[3] > 0.f ? acc0[3] : 0.f) * w2v.w;
    v1 += (acc1[0] > 0.f ? acc1[0] : 0.f) * w2v.x;
    v1 += (acc1[1] > 0.f ? acc1[1] : 0.f) * w2v.y;
    v1 += (acc1[2] > 0.f ? acc1[2] : 0.f) * w2v.z;
    v1 += (acc1[3] > 0.f ? acc1[3] : 0.f) * w2v.w;
#pragma unroll
    for (int o = 1; o < 32; o <<= 1) {
        v0 += __shfl_xor(v0, o, 64);
        v1 += __shfl_xor(v1, o, 64);
    }
    if (cg == 0) {
        out[a0 + ap * 2]     = v0 + b2[0];
        out[a0 + ap * 2 + 1] = v1 + b2[0];
    }
}

// ---------------- launch ----------------

extern "C" void kernel_launch(void* const* d_in, const int* in_sizes, int n_in,
                              void* d_out, int out_size, void* d_ws, size_t ws_size,
                              hipStream_t stream) {
    const float* x   = (const float*)d_in[0];
    const int* ei    = (const int*)d_in[1];
    const int* asrc  = (const int*)d_in[2];
    const int* adst  = (const int*)d_in[3];
    const int* atype = (const int*)d_in[4];
    const float* gW  = (const float*)d_in[5];
    const float* gas = (const float*)d_in[6];
    const float* gad = (const float*)d_in[7];
    const float* gb  = (const float*)d_in[8];
    const float* W1  = (const float*)d_in[9];
    const float* b1  = (const float*)d_in[10];
    const float* W2  = (const float*)d_in[11];
    const float* b2  = (const float*)d_in[12];
    float* out = (float*)d_out;

    __half* z16A = (__half*)d_ws;                       // 2.56 MB
    __half* z16B = z16A + N_NODES * HID;                // 2.56 MB
    float* H    = (float*)(z16B + N_NODES * HID);       // 5.12 MB (shared h buffer)
    float* zsA  = H + N_NODES * HID;
    float* zdA  = zsA + N_NODES;
    float* zsB  = zdA + N_NODES;
    float* zdB  = zsB + N_NODES;
    int* offs   = (int*)(zdB + N_NODES);
    int* csr    = offs + (N_NODES + 1);
    int* bcnt   = csr + TOT_E;
    unsigned* bpart = (unsigned*)(bcnt + P1_BLOCKS * 256);

    part1_k<<<P1_BLOCKS, 256, 0, stream>>>(ei, bpart, bcnt);
    g2_k<<<G_BLOCKS + NBKT, 256, 0, stream>>>(x, gW, gas, gad, z16A, zsA, zdA,
                                              bpart, bcnt, csr, offs);

    // layer 1: agg -> H -> gemm -> z16B
    agg_k<<<AGG_B, 256, 0, stream>>>(z16A, zsA, zdA, offs, csr, gb, H);
    gemmh_k<<<G_BLOCKS, 256, 0, stream>>>(H, gW + 1 * HID * HID, gas + 1 * HID,
                                          gad + 1 * HID, z16B, zsB, zdB);
    // layer 2: agg -> H -> gemm -> z16A
    agg_k<<<AGG_B, 256, 0, stream>>>(z16B, zsB, zdB, offs, csr, gb + 1 * HID, H);
    gemmh_k<<<G_BLOCKS, 256, 0, stream>>>(H, gW + 2 * HID * HID, gas + 2 * HID,
                                          gad + 2 * HID, z16A, zsA, zdA);
    // layer 3: agg -> H (final node embeddings)
    agg_k<<<AGG_B, 256, 0, stream>>>(z16A, zsA, zdA, offs, csr, gb + 2 * HID, H);

    score_k<<<N_ACT / SC_APB, 256, 0, stream>>>(H, asrc, adst, atype,
                                                W1, b1, W2, b2, out);
}